// Round 8
// baseline (206.157 us; speedup 1.0000x reference)
//
#include <hip/hip_runtime.h>

typedef unsigned short u16;
typedef _Float16 f16x8 __attribute__((ext_vector_type(8)));
typedef __fp16 hf16x2 __attribute__((ext_vector_type(2)));
typedef float f32x4 __attribute__((ext_vector_type(4)));
typedef float f32x16 __attribute__((ext_vector_type(16)));

#define NB 8
#define NC 512
#define NHD 8
#define DH 64
#define NN 1024
#define LOG2E 1.4426950408889634f

__device__ __forceinline__ u16 f2h(float f) {
    union { _Float16 h; u16 u; } v; v.h = (_Float16)f;
    return v.u;
}

// ================= kernel 1: fused prep =================
// blocks [0,2048): transpose x/d [b,c,n] -> [b,n,c] fp16
// blocks [2048,5120): convert Wq/Wk/Wv fp32 -> fp16
// blocks [5120,7168): pos[h,i,d] = rel_h + rel_w fp16
__global__ __launch_bounds__(256) void k_prep(
    const float* __restrict__ x, const float* __restrict__ d,
    const float* __restrict__ Wq, const float* __restrict__ Wk, const float* __restrict__ Wv,
    const float* __restrict__ relh, const float* __restrict__ relw,
    u16* __restrict__ xt, u16* __restrict__ dt,
    u16* __restrict__ wq, u16* __restrict__ wk, u16* __restrict__ wv,
    u16* __restrict__ ps) {
    __shared__ float tile[64][65];
    int id = blockIdx.x, t = threadIdx.x;
    if (id < 2048) {
        // ---- transpose+cvt ----
        int nb = (id & 15) * 64;
        int cb = ((id >> 4) & 7) * 64;
        int z = id >> 7;
        int b = z & 7;
        const float* src = (z >> 3) ? d : x;
        u16* ot = (z >> 3) ? dt : xt;
        {
            int crow = t >> 2, n0 = (t & 3) * 16;
            const float* g = src + ((size_t)(b * NC + cb + crow)) * NN + nb + n0;
#pragma unroll
            for (int k = 0; k < 16; k += 4) {
                float4 v = *(const float4*)(g + k);
                tile[crow][n0 + k + 0] = v.x;
                tile[crow][n0 + k + 1] = v.y;
                tile[crow][n0 + k + 2] = v.z;
                tile[crow][n0 + k + 3] = v.w;
            }
        }
        __syncthreads();
        {
            int nrow = t >> 2, c0 = (t & 3) * 16;
            union { u16 s[16]; uint4 v[2]; } uh;
#pragma unroll
            for (int k = 0; k < 16; ++k) uh.s[k] = f2h(tile[c0 + k][nrow]);
            size_t oidx = ((size_t)(b * NN + nb + nrow)) * NC + cb + c0;
            *(uint4*)(ot + oidx)     = uh.v[0];
            *(uint4*)(ot + oidx + 8) = uh.v[1];
        }
    } else if (id < 5120) {
        int j = id - 2048;
        int m = j >> 10;
        int i = (j & 1023) * 256 + t;
        const float* src = (m == 0) ? Wq : (m == 1) ? Wk : Wv;
        u16* dst = (m == 0) ? wq : (m == 1) ? wk : wv;
        dst[i] = f2h(src[i]);
    } else {
        int idx = (id - 5120) * 256 + t;
        int dd = idx & 63;
        int i  = (idx >> 6) & 1023;
        int h  = idx >> 16;
        float f = relh[(h * 64 + dd) * 32 + (i & 31)] + relw[(h * 64 + dd) * 32 + (i >> 5)];
        ps[(h * 1024 + i) * 64 + dd] = f2h(f);
    }
}

// ================= kernel 2: projection GEMM, fp16, global_load_lds staging =================
// q output is PRE-SCALED by log2(e) (softmax runs in exp2 domain).
__global__ __launch_bounds__(256) void k_proj(
    const u16* __restrict__ xt, const u16* __restrict__ dt,
    const u16* __restrict__ wq, const u16* __restrict__ wk, const u16* __restrict__ wv,
    const float* __restrict__ bq, const float* __restrict__ bk, const float* __restrict__ bv,
    u16* __restrict__ qt_o, u16* __restrict__ kt_o, u16* __restrict__ v_o) {
    __shared__ u16 Asm[128 * 32];   // UNPADDED: required by global_load_lds lane mapping
    __shared__ u16 Bsm[128 * 32];

    int p = blockIdx.z % 3;
    int b = blockIdx.z / 3;
    const u16 *Ap, *Bp;
    const float* bias;
    u16* Oq;
    if (p == 0)      { Ap = wq; Bp = xt; bias = bq; Oq = qt_o; }
    else if (p == 1) { Ap = wk; Bp = dt; bias = bk; Oq = kt_o; }
    else             { Ap = wv; Bp = dt; bias = bv; Oq = v_o; }
    Bp += (size_t)b * NN * NC;
    float oscale = (p == 0) ? LOG2E : 1.0f;

    int obase = blockIdx.x * 128;
    int nbase = blockIdx.y * 128;
    int t = threadIdx.x, wave = t >> 6, quad = (t & 63) >> 4, l15 = t & 15;
    int wr = (wave >> 1) * 64, wc = (wave & 1) * 64;

    f32x4 acc[4][4];
#pragma unroll
    for (int fo = 0; fo < 4; ++fo)
#pragma unroll
        for (int fn = 0; fn < 4; ++fn)
#pragma unroll
            for (int r = 0; r < 4; ++r) acc[fo][fn][r] = 0.f;

    for (int kk = 0; kk < NC; kk += 32) {
        __syncthreads();
#pragma unroll
        for (int u = 0; u < 2; ++u) {
            int c = u * 256 + t;
            int row = c >> 2, part = c & 3;
            __builtin_amdgcn_global_load_lds(
                (const __attribute__((address_space(1))) void*)(Ap + (size_t)(obase + row) * NC + kk + part * 8),
                (__attribute__((address_space(3))) void*)(Asm + (size_t)(u * 256 + wave * 64) * 8), 16, 0, 0);
            __builtin_amdgcn_global_load_lds(
                (const __attribute__((address_space(1))) void*)(Bp + (size_t)(nbase + row) * NC + kk + part * 8),
                (__attribute__((address_space(3))) void*)(Bsm + (size_t)(u * 256 + wave * 64) * 8), 16, 0, 0);
        }
        __syncthreads();

        f16x8 af[4], bfr[4];
#pragma unroll
        for (int fo = 0; fo < 4; ++fo) af[fo] = *(const f16x8*)&Asm[(wr + fo * 16 + l15) * 32 + quad * 8];
#pragma unroll
        for (int fn = 0; fn < 4; ++fn) bfr[fn] = *(const f16x8*)&Bsm[(wc + fn * 16 + l15) * 32 + quad * 8];
#pragma unroll
        for (int fo = 0; fo < 4; ++fo)
#pragma unroll
            for (int fn = 0; fn < 4; ++fn)
                acc[fo][fn] = __builtin_amdgcn_mfma_f32_16x16x32_f16(af[fo], bfr[fn], acc[fo][fn], 0, 0, 0);
    }

#pragma unroll
    for (int fo = 0; fo < 4; ++fo) {
#pragma unroll
        for (int fn = 0; fn < 4; ++fn) {
            int o0 = obase + wr + fo * 16 + quad * 4;     // 4-aligned, never crosses a head
            int n = nbase + wc + fn * 16 + l15;
            if (p < 2) {
                union { u16 s[4]; uint2 v2; } uh;
#pragma unroll
                for (int r = 0; r < 4; ++r) uh.s[r] = f2h((acc[fo][fn][r] + bias[o0 + r]) * oscale);
                int head = o0 >> 6, dd0 = o0 & 63;
                size_t idx = (((size_t)(b * NHD + head) * NN) + n) * DH + dd0;
                *(uint2*)&Oq[idx] = uh.v2;
            } else {
#pragma unroll
                for (int r = 0; r < 4; ++r) {
                    int o = o0 + r;
                    int head = o >> 6, dd = o & 63;
                    Oq[((size_t)(b * NHD + head) * DH + dd) * NN + n] = f2h(acc[fo][fn][r] + bias[o]);
                }
            }
        }
    }
}

// ================= kernel 3: fused flash attention v6 =================
// Round-5 structure (2 barriers/iter, Pt separate, 68 KB LDS, grid 512 = 2
// blocks/CU) + REGISTER PREFETCH of the next j-chunk: global loads issue at
// the top of compute(n) into VGPRs; the write phase at iter n+1 is pure
// VGPR->LDS so the pre-barrier drain is lgkm-only (no exposed global latency).
__global__ __launch_bounds__(256, 2) void k_attn(
    const u16* __restrict__ qt, const u16* __restrict__ kt,
    const u16* __restrict__ v_, const u16* __restrict__ pos,
    float* __restrict__ out) {
    __shared__ u16 Bs[128 * 132];      // rows j: [K(64) | Q(64)], pad 4 (2-way = free)
    __shared__ u16 Vt[64 * 132];       // [d][j 128], pad 4
    __shared__ u16 Pt[4 * 32 * 68];    // wave-private [i 32][j 64] strips, pad 4

    // XCD swizzle: all 8 i-blocks of group g=(b,head) land on XCD g%8
    int n = blockIdx.x;
    int g = n & 63;
    int ib = n >> 6;
    int head = g & 7, b = g >> 3;

    int t = threadIdx.x, ws = t >> 6, lane = t & 63, h = lane >> 5, l31 = lane & 31;
    size_t bh = (size_t)(b * NHD + head);
    const u16* qb = qt + bh * NN * DH;
    const u16* kb = kt + bh * NN * DH;
    const u16* vb = v_ + bh * DH * NN;
    const u16* pb = pos + (size_t)head * NN * DH;
    int i0 = ib * 128;
    int iglob = i0 + ws * 32 + l31;

    // wave-private B-operand frags: k 0..63 = q_i (pre-scaled by log2e), 64..127 = pos_i
    f16x8 qf[8];
#pragma unroll
    for (int ks = 0; ks < 4; ++ks) qf[ks] = *(const f16x8*)&qb[(size_t)iglob * DH + ks * 16 + h * 8];
#pragma unroll
    for (int ks = 4; ks < 8; ++ks) qf[ks] = *(const f16x8*)&pb[(size_t)iglob * DH + (ks - 4) * 16 + h * 8];

    // ---- prefetch pointers (per-thread, fixed LDS dst, advancing global src) ----
    // Bs: u in 0..7: c=u*256+t, row=u*16+(t>>4), gg=t&15; src row-major [j][64]
    // Vt: u in 0..3: c=u*256+t, row=u*16+(t>>4) (d), col gg*8 in j
    int t4 = t >> 4, gg = t & 15;
    const u16* pbsrc[8];
    const u16* pvsrc[4];
    int bcol = (gg & 7) * 8;
    const u16* kq = (gg < 8) ? kb : qb;
#pragma unroll
    for (int u = 0; u < 8; ++u) pbsrc[u] = kq + (size_t)(u * 16 + t4) * DH + bcol;
#pragma unroll
    for (int u = 0; u < 4; ++u) pvsrc[u] = vb + (size_t)(u * 16 + t4) * NN + gg * 8;
    int bdst[8], vdst[4];
#pragma unroll
    for (int u = 0; u < 8; ++u) bdst[u] = (u * 16 + t4) * 132 + gg * 8;
#pragma unroll
    for (int u = 0; u < 4; ++u) vdst[u] = (u * 16 + t4) * 132 + gg * 8;

    uint4 preb[8], prev[4];
    // prologue: load chunk 0
#pragma unroll
    for (int u = 0; u < 8; ++u) { preb[u] = *(const uint4*)pbsrc[u]; pbsrc[u] += 128 * DH; }
#pragma unroll
    for (int u = 0; u < 4; ++u) { prev[u] = *(const uint4*)pvsrc[u]; pvsrc[u] += 128; }

    f32x16 oacc[2];
#pragma unroll
    for (int df = 0; df < 2; ++df)
#pragma unroll
        for (int r = 0; r < 16; ++r) oacc[df][r] = 0.f;
    float m_ = -__builtin_inff(), l_ = 0.f;
    int ptb = ws * 32 * 68;

    for (int jc = 0; jc < NN; jc += 128) {
        // ---- write staged regs -> LDS (prev compute's reads done: end-of-iter barrier) ----
#pragma unroll
        for (int u = 0; u < 8; ++u) *(uint4*)&Bs[bdst[u]] = preb[u];
#pragma unroll
        for (int u = 0; u < 4; ++u) *(uint4*)&Vt[vdst[u]] = prev[u];
        __syncthreads();   // lgkm-only drain; LDS tiles valid

        // ---- issue prefetch for next chunk (lands during compute; last-iter
        //      loads read the adjacent ws array -- harmless, never written) ----
#pragma unroll
        for (int u = 0; u < 8; ++u) { preb[u] = *(const uint4*)pbsrc[u]; pbsrc[u] += 128 * DH; }
#pragma unroll
        for (int u = 0; u < 4; ++u) { prev[u] = *(const uint4*)pvsrc[u]; pvsrc[u] += 128; }

        // ---- S^T: 4 j-frags of 32 rows, extended K=128 over 8 ks ----
        f32x16 sacc[4];
#pragma unroll
        for (int jf = 0; jf < 4; ++jf)
#pragma unroll
            for (int r = 0; r < 16; ++r) sacc[jf][r] = 0.f;
#pragma unroll
        for (int jf = 0; jf < 4; ++jf)
#pragma unroll
            for (int ks = 0; ks < 8; ++ks) {
                f16x8 af = *(const f16x8*)&Bs[(jf * 32 + l31) * 132 + ks * 16 + h * 8];
                sacc[jf] = __builtin_amdgcn_mfma_f32_32x32x16_f16(af, qf[ks], sacc[jf], 0, 0, 0);
            }

        // ---- online softmax over 128 j (exp2 domain; S is pre-scaled by log2e) ----
        float mloc = -__builtin_inff();
#pragma unroll
        for (int jf = 0; jf < 4; ++jf)
#pragma unroll
            for (int r = 0; r < 16; ++r) mloc = fmaxf(mloc, sacc[jf][r]);
        mloc = fmaxf(mloc, __shfl_xor(mloc, 32));
        if (__any(mloc > m_)) {
            float mnew = fmaxf(m_, mloc);
            float alpha = __builtin_amdgcn_exp2f(m_ - mnew);
            m_ = mnew;
#pragma unroll
            for (int df = 0; df < 2; ++df)
#pragma unroll
                for (int r = 0; r < 16; ++r) oacc[df][r] *= alpha;
            l_ *= alpha;
        }
        float lsum = 0.f;
#pragma unroll
        for (int jf = 0; jf < 4; ++jf)
#pragma unroll
            for (int r = 0; r < 16; ++r) {
                float pv = __builtin_amdgcn_exp2f(sacc[jf][r] - m_);
                sacc[jf][r] = pv;
                lsum += pv;
            }
        lsum += __shfl_xor(lsum, 32);
        l_ += lsum;

        // ---- P->Pt (wave-private, no barrier) + PV, in two 64-j halves ----
#pragma unroll
        for (int half = 0; half < 2; ++half) {
#pragma unroll
            for (int jf = 0; jf < 2; ++jf) {
                int jfg = half * 2 + jf;
#pragma unroll
                for (int mm = 0; mm < 4; ++mm) {
                    union { hf16x2 v; unsigned u; } p0, p1;
                    p0.v = __builtin_amdgcn_cvt_pkrtz(sacc[jfg][mm * 4 + 0], sacc[jfg][mm * 4 + 1]);
                    p1.v = __builtin_amdgcn_cvt_pkrtz(sacc[jfg][mm * 4 + 2], sacc[jfg][mm * 4 + 3]);
                    uint2 w; w.x = p0.u; w.y = p1.u;
                    *(uint2*)&Pt[ptb + l31 * 68 + jf * 32 + 4 * h + 8 * mm] = w;
                }
            }
#pragma unroll
            for (int jw = 0; jw < 4; ++jw) {
                f16x8 pf = *(const f16x8*)&Pt[ptb + l31 * 68 + jw * 16 + h * 8];
#pragma unroll
                for (int df = 0; df < 2; ++df) {
                    f16x8 vf = *(const f16x8*)&Vt[(df * 32 + l31) * 132 + half * 64 + jw * 16 + h * 8];
                    oacc[df] = __builtin_amdgcn_mfma_f32_32x32x16_f16(vf, pf, oacc[df], 0, 0, 0);
                }
            }
        }
        __syncthreads();   // all reads of Bs/Vt done before next write phase
    }

    // ---- epilogue ----
    float li = 1.0f / l_;
#pragma unroll
    for (int df = 0; df < 2; ++df)
#pragma unroll
        for (int r = 0; r < 16; ++r) {
            int dd = df * 32 + (r & 3) + 8 * (r >> 2) + 4 * h;
            out[((size_t)(b * NC) + head * DH + dd) * NN + i0 + ws * 32 + l31] = oacc[df][r] * li;
        }
}

// ================= workspace layout (bytes) =================
#define SXT  (8u * 1024u * 512u * 2u)      /* 8 MB: [B,N,C] fp16 */
#define SW   (512u * 512u * 2u)
#define SQT  SXT
#define SPOS (8u * 1024u * 64u * 2u)

#define OFF_XT   (0u)
#define OFF_DT   (OFF_XT + SXT)
#define OFF_WQ   (OFF_DT + SXT)
#define OFF_WK   (OFF_WQ + SW)
#define OFF_WV   (OFF_WK + SW)
#define OFF_QT   (OFF_WV + SW)
#define OFF_KT   (OFF_QT + SQT)
#define OFF_V    (OFF_KT + SQT)
#define OFF_POS  (OFF_V + SQT)
// total = 5*8388608 + 3*524288 + 1048576 = 44,564,480 bytes (~42.5 MiB)
// NOTE: k_attn's last-iteration prefetch reads up to 16 KB past kt/qt/v_ ends;
// all of those land inside later ws arrays (valid mapped memory, never written).

extern "C" void kernel_launch(void* const* d_in, const int* in_sizes, int n_in,
                              void* d_out, int out_size, void* d_ws, size_t ws_size,
                              hipStream_t stream) {
    const float* x   = (const float*)d_in[0];
    const float* d   = (const float*)d_in[1];
    const float* Wq  = (const float*)d_in[2];
    const float* bq  = (const float*)d_in[3];
    const float* Wk  = (const float*)d_in[4];
    const float* bk  = (const float*)d_in[5];
    const float* Wv  = (const float*)d_in[6];
    const float* bv  = (const float*)d_in[7];
    const float* rh  = (const float*)d_in[8];
    const float* rw  = (const float*)d_in[9];

    char* ws = (char*)d_ws;
    u16* xt = (u16*)(ws + OFF_XT);
    u16* dt = (u16*)(ws + OFF_DT);
    u16* wq = (u16*)(ws + OFF_WQ);
    u16* wk = (u16*)(ws + OFF_WK);
    u16* wv = (u16*)(ws + OFF_WV);
    u16* qt = (u16*)(ws + OFF_QT);
    u16* kt = (u16*)(ws + OFF_KT);
    u16* v_ = (u16*)(ws + OFF_V);
    u16* ps = (u16*)(ws + OFF_POS);

    k_prep<<<7168, 256, 0, stream>>>(x, d, Wq, Wk, Wv, rh, rw, xt, dt, wq, wk, wv, ps);
    k_proj<<<dim3(4, 8, 24), 256, 0, stream>>>(xt, dt, wq, wk, wv, bq, bk, bv, qt, kt, v_);
    k_attn<<<512, 256, 0, stream>>>(qt, kt, v_, ps, (float*)d_out);
}

// Round 9
// 167.187 us; speedup vs baseline: 1.2331x; 1.2331x over previous
//
#include <hip/hip_runtime.h>

typedef unsigned short u16;
typedef _Float16 f16x8 __attribute__((ext_vector_type(8)));
typedef __fp16 hf16x2 __attribute__((ext_vector_type(2)));
typedef float f32x4 __attribute__((ext_vector_type(4)));
typedef float f32x16 __attribute__((ext_vector_type(16)));

#define NB 8
#define NC 512
#define NHD 8
#define DH 64
#define NN 1024
#define LOG2E 1.4426950408889634f

__device__ __forceinline__ u16 f2h(float f) {
    union { _Float16 h; u16 u; } v; v.h = (_Float16)f;
    return v.u;
}

// ================= kernel 1: fused prep =================
// blocks [0,2048): transpose x/d [b,c,n] -> [b,n,c] fp16
// blocks [2048,5120): convert Wq/Wk/Wv fp32 -> fp16
// blocks [5120,7168): pos[h,i,d] = rel_h + rel_w fp16
__global__ __launch_bounds__(256) void k_prep(
    const float* __restrict__ x, const float* __restrict__ d,
    const float* __restrict__ Wq, const float* __restrict__ Wk, const float* __restrict__ Wv,
    const float* __restrict__ relh, const float* __restrict__ relw,
    u16* __restrict__ xt, u16* __restrict__ dt,
    u16* __restrict__ wq, u16* __restrict__ wk, u16* __restrict__ wv,
    u16* __restrict__ ps) {
    __shared__ float tile[64][65];
    int id = blockIdx.x, t = threadIdx.x;
    if (id < 2048) {
        // ---- transpose+cvt ----
        int nb = (id & 15) * 64;
        int cb = ((id >> 4) & 7) * 64;
        int z = id >> 7;
        int b = z & 7;
        const float* src = (z >> 3) ? d : x;
        u16* ot = (z >> 3) ? dt : xt;
        {
            int crow = t >> 2, n0 = (t & 3) * 16;
            const float* g = src + ((size_t)(b * NC + cb + crow)) * NN + nb + n0;
#pragma unroll
            for (int k = 0; k < 16; k += 4) {
                float4 v = *(const float4*)(g + k);
                tile[crow][n0 + k + 0] = v.x;
                tile[crow][n0 + k + 1] = v.y;
                tile[crow][n0 + k + 2] = v.z;
                tile[crow][n0 + k + 3] = v.w;
            }
        }
        __syncthreads();
        {
            int nrow = t >> 2, c0 = (t & 3) * 16;
            union { u16 s[16]; uint4 v[2]; } uh;
#pragma unroll
            for (int k = 0; k < 16; ++k) uh.s[k] = f2h(tile[c0 + k][nrow]);
            size_t oidx = ((size_t)(b * NN + nb + nrow)) * NC + cb + c0;
            *(uint4*)(ot + oidx)     = uh.v[0];
            *(uint4*)(ot + oidx + 8) = uh.v[1];
        }
    } else if (id < 5120) {
        int j = id - 2048;
        int m = j >> 10;
        int i = (j & 1023) * 256 + t;
        const float* src = (m == 0) ? Wq : (m == 1) ? Wk : Wv;
        u16* dst = (m == 0) ? wq : (m == 1) ? wk : wv;
        dst[i] = f2h(src[i]);
    } else {
        int idx = (id - 5120) * 256 + t;
        int dd = idx & 63;
        int i  = (idx >> 6) & 1023;
        int h  = idx >> 16;
        float f = relh[(h * 64 + dd) * 32 + (i & 31)] + relw[(h * 64 + dd) * 32 + (i >> 5)];
        ps[(h * 1024 + i) * 64 + dd] = f2h(f);
    }
}

// ================= kernel 2: projection GEMM, fp16, global_load_lds staging =================
// q output is PRE-SCALED by log2(e) (softmax runs in exp2 domain; both S terms
// carry exactly one factor of q, so S arrives scaled by log2e).
__global__ __launch_bounds__(256) void k_proj(
    const u16* __restrict__ xt, const u16* __restrict__ dt,
    const u16* __restrict__ wq, const u16* __restrict__ wk, const u16* __restrict__ wv,
    const float* __restrict__ bq, const float* __restrict__ bk, const float* __restrict__ bv,
    u16* __restrict__ qt_o, u16* __restrict__ kt_o, u16* __restrict__ v_o) {
    __shared__ u16 Asm[128 * 32];   // UNPADDED: required by global_load_lds lane mapping
    __shared__ u16 Bsm[128 * 32];

    int p = blockIdx.z % 3;
    int b = blockIdx.z / 3;
    const u16 *Ap, *Bp;
    const float* bias;
    u16* Oq;
    if (p == 0)      { Ap = wq; Bp = xt; bias = bq; Oq = qt_o; }
    else if (p == 1) { Ap = wk; Bp = dt; bias = bk; Oq = kt_o; }
    else             { Ap = wv; Bp = dt; bias = bv; Oq = v_o; }
    Bp += (size_t)b * NN * NC;
    float oscale = (p == 0) ? LOG2E : 1.0f;

    int obase = blockIdx.x * 128;
    int nbase = blockIdx.y * 128;
    int t = threadIdx.x, wave = t >> 6, quad = (t & 63) >> 4, l15 = t & 15;
    int wr = (wave >> 1) * 64, wc = (wave & 1) * 64;

    f32x4 acc[4][4];
#pragma unroll
    for (int fo = 0; fo < 4; ++fo)
#pragma unroll
        for (int fn = 0; fn < 4; ++fn)
#pragma unroll
            for (int r = 0; r < 4; ++r) acc[fo][fn][r] = 0.f;

    for (int kk = 0; kk < NC; kk += 32) {
        __syncthreads();
#pragma unroll
        for (int u = 0; u < 2; ++u) {
            int c = u * 256 + t;
            int row = c >> 2, part = c & 3;
            __builtin_amdgcn_global_load_lds(
                (const __attribute__((address_space(1))) void*)(Ap + (size_t)(obase + row) * NC + kk + part * 8),
                (__attribute__((address_space(3))) void*)(Asm + (size_t)(u * 256 + wave * 64) * 8), 16, 0, 0);
            __builtin_amdgcn_global_load_lds(
                (const __attribute__((address_space(1))) void*)(Bp + (size_t)(nbase + row) * NC + kk + part * 8),
                (__attribute__((address_space(3))) void*)(Bsm + (size_t)(u * 256 + wave * 64) * 8), 16, 0, 0);
        }
        __syncthreads();

        f16x8 af[4], bfr[4];
#pragma unroll
        for (int fo = 0; fo < 4; ++fo) af[fo] = *(const f16x8*)&Asm[(wr + fo * 16 + l15) * 32 + quad * 8];
#pragma unroll
        for (int fn = 0; fn < 4; ++fn) bfr[fn] = *(const f16x8*)&Bsm[(wc + fn * 16 + l15) * 32 + quad * 8];
#pragma unroll
        for (int fo = 0; fo < 4; ++fo)
#pragma unroll
            for (int fn = 0; fn < 4; ++fn)
                acc[fo][fn] = __builtin_amdgcn_mfma_f32_16x16x32_f16(af[fo], bfr[fn], acc[fo][fn], 0, 0, 0);
    }

#pragma unroll
    for (int fo = 0; fo < 4; ++fo) {
#pragma unroll
        for (int fn = 0; fn < 4; ++fn) {
            int o0 = obase + wr + fo * 16 + quad * 4;     // 4-aligned, never crosses a head
            int n = nbase + wc + fn * 16 + l15;
            if (p < 2) {
                union { u16 s[4]; uint2 v2; } uh;
#pragma unroll
                for (int r = 0; r < 4; ++r) uh.s[r] = f2h((acc[fo][fn][r] + bias[o0 + r]) * oscale);
                int head = o0 >> 6, dd0 = o0 & 63;
                size_t idx = (((size_t)(b * NHD + head) * NN) + n) * DH + dd0;
                *(uint2*)&Oq[idx] = uh.v2;
            } else {
#pragma unroll
                for (int r = 0; r < 4; ++r) {
                    int o = o0 + r;
                    int head = o >> 6, dd = o & 63;
                    Oq[((size_t)(b * NHD + head) * DH + dd) * NN + n] = f2h(acc[fo][fn][r] + bias[o]);
                }
            }
        }
    }
}

// ================= kernel 3: fused flash attention (round-5 configuration) =================
// S^T, 32x32x16 fp16 MFMA, 128-j chunks, exp2-domain softmax, XCD-swizzled grid.
// Session-best config: 2 barriers/iter, Pt separate (68 KB LDS), launch_bounds
// (256,2), grid 512 (= 2 blocks/CU, grid-limited). Attempts that regressed:
//  - r6: Pt aliased into Bs + 3rd barrier (+11 us serialization)
//  - r6: __launch_bounds__(256,3) -> VGPR clamp 84, spills, 2x slower
//  - r8: register prefetch of next chunk -> allocator spills 207 MB, 2x slower
__global__ __launch_bounds__(256, 2) void k_attn(
    const u16* __restrict__ qt, const u16* __restrict__ kt,
    const u16* __restrict__ v_, const u16* __restrict__ pos,
    float* __restrict__ out) {
    __shared__ u16 Bs[128 * 132];      // rows j: [K(64) | Q(64)], pad 4 (2-way = free)
    __shared__ u16 Vt[64 * 132];       // [d][j 128], pad 4
    __shared__ u16 Pt[4 * 32 * 68];    // wave-private [i 32][j 64] strips, pad 4

    // XCD swizzle: all 8 i-blocks of group g=(b,head) land on XCD g%8
    int n = blockIdx.x;
    int g = n & 63;
    int ib = n >> 6;
    int head = g & 7, b = g >> 3;

    int t = threadIdx.x, ws = t >> 6, lane = t & 63, h = lane >> 5, l31 = lane & 31;
    size_t bh = (size_t)(b * NHD + head);
    const u16* qb = qt + bh * NN * DH;
    const u16* kb = kt + bh * NN * DH;
    const u16* vb = v_ + bh * DH * NN;
    const u16* pb = pos + (size_t)head * NN * DH;
    int i0 = ib * 128;
    int iglob = i0 + ws * 32 + l31;

    // wave-private B-operand frags: k 0..63 = q_i (pre-scaled by log2e), 64..127 = pos_i
    f16x8 qf[8];
#pragma unroll
    for (int ks = 0; ks < 4; ++ks) qf[ks] = *(const f16x8*)&qb[(size_t)iglob * DH + ks * 16 + h * 8];
#pragma unroll
    for (int ks = 4; ks < 8; ++ks) qf[ks] = *(const f16x8*)&pb[(size_t)iglob * DH + (ks - 4) * 16 + h * 8];

    f32x16 oacc[2];
#pragma unroll
    for (int df = 0; df < 2; ++df)
#pragma unroll
        for (int r = 0; r < 16; ++r) oacc[df][r] = 0.f;
    float m_ = -__builtin_inff(), l_ = 0.f;
    int ptb = ws * 32 * 68;

    for (int jc = 0; jc < NN; jc += 128) {
        __syncthreads();
        // stage Bs: 128 rows x 16 chunks = 2048, 8/thread
#pragma unroll
        for (int u = 0; u < 8; ++u) {
            int c = u * 256 + t;
            int row = c >> 4, gg = c & 15;
            const u16* src = (gg < 8) ? &kb[(size_t)(jc + row) * DH + gg * 8]
                                      : &qb[(size_t)(jc + row) * DH + (gg - 8) * 8];
            *(uint4*)&Bs[row * 132 + gg * 8] = *(const uint4*)src;
        }
        // stage Vt: 64 rows x 16 chunks = 1024, 4/thread
#pragma unroll
        for (int u = 0; u < 4; ++u) {
            int c = u * 256 + t;
            int row = c >> 4, gg = c & 15;
            *(uint4*)&Vt[row * 132 + gg * 8] = *(const uint4*)&vb[(size_t)row * NN + jc + gg * 8];
        }
        __syncthreads();

        // ---- S^T: 4 j-frags of 32 rows, extended K=128 over 8 ks ----
        f32x16 sacc[4];
#pragma unroll
        for (int jf = 0; jf < 4; ++jf)
#pragma unroll
            for (int r = 0; r < 16; ++r) sacc[jf][r] = 0.f;
#pragma unroll
        for (int jf = 0; jf < 4; ++jf)
#pragma unroll
            for (int ks = 0; ks < 8; ++ks) {
                f16x8 af = *(const f16x8*)&Bs[(jf * 32 + l31) * 132 + ks * 16 + h * 8];
                sacc[jf] = __builtin_amdgcn_mfma_f32_32x32x16_f16(af, qf[ks], sacc[jf], 0, 0, 0);
            }

        // ---- online softmax over 128 j (exp2 domain; S is pre-scaled by log2e) ----
        float mloc = -__builtin_inff();
#pragma unroll
        for (int jf = 0; jf < 4; ++jf)
#pragma unroll
            for (int r = 0; r < 16; ++r) mloc = fmaxf(mloc, sacc[jf][r]);
        mloc = fmaxf(mloc, __shfl_xor(mloc, 32));
        if (__any(mloc > m_)) {
            float mnew = fmaxf(m_, mloc);
            float alpha = __builtin_amdgcn_exp2f(m_ - mnew);
            m_ = mnew;
#pragma unroll
            for (int df = 0; df < 2; ++df)
#pragma unroll
                for (int r = 0; r < 16; ++r) oacc[df][r] *= alpha;
            l_ *= alpha;
        }
        float lsum = 0.f;
#pragma unroll
        for (int jf = 0; jf < 4; ++jf)
#pragma unroll
            for (int r = 0; r < 16; ++r) {
                float pv = __builtin_amdgcn_exp2f(sacc[jf][r] - m_);
                sacc[jf][r] = pv;
                lsum += pv;
            }
        lsum += __shfl_xor(lsum, 32);
        l_ += lsum;

        // ---- P->Pt (wave-private, no barrier) + PV, in two 64-j halves ----
#pragma unroll
        for (int half = 0; half < 2; ++half) {
#pragma unroll
            for (int jf = 0; jf < 2; ++jf) {
                int jfg = half * 2 + jf;
#pragma unroll
                for (int mm = 0; mm < 4; ++mm) {
                    union { hf16x2 v; unsigned u; } p0, p1;
                    p0.v = __builtin_amdgcn_cvt_pkrtz(sacc[jfg][mm * 4 + 0], sacc[jfg][mm * 4 + 1]);
                    p1.v = __builtin_amdgcn_cvt_pkrtz(sacc[jfg][mm * 4 + 2], sacc[jfg][mm * 4 + 3]);
                    uint2 w; w.x = p0.u; w.y = p1.u;
                    *(uint2*)&Pt[ptb + l31 * 68 + jf * 32 + 4 * h + 8 * mm] = w;
                }
            }
#pragma unroll
            for (int jw = 0; jw < 4; ++jw) {
                f16x8 pf = *(const f16x8*)&Pt[ptb + l31 * 68 + jw * 16 + h * 8];
#pragma unroll
                for (int df = 0; df < 2; ++df) {
                    f16x8 vf = *(const f16x8*)&Vt[(df * 32 + l31) * 132 + half * 64 + jw * 16 + h * 8];
                    oacc[df] = __builtin_amdgcn_mfma_f32_32x32x16_f16(vf, pf, oacc[df], 0, 0, 0);
                }
            }
        }
    }

    // ---- epilogue ----
    float li = 1.0f / l_;
#pragma unroll
    for (int df = 0; df < 2; ++df)
#pragma unroll
        for (int r = 0; r < 16; ++r) {
            int dd = df * 32 + (r & 3) + 8 * (r >> 2) + 4 * h;
            out[((size_t)(b * NC) + head * DH + dd) * NN + i0 + ws * 32 + l31] = oacc[df][r] * li;
        }
}

// ================= workspace layout (bytes) =================
#define SXT  (8u * 1024u * 512u * 2u)      /* 8 MB: [B,N,C] fp16 */
#define SW   (512u * 512u * 2u)
#define SQT  SXT
#define SPOS (8u * 1024u * 64u * 2u)

#define OFF_XT   (0u)
#define OFF_DT   (OFF_XT + SXT)
#define OFF_WQ   (OFF_DT + SXT)
#define OFF_WK   (OFF_WQ + SW)
#define OFF_WV   (OFF_WK + SW)
#define OFF_QT   (OFF_WV + SW)
#define OFF_KT   (OFF_QT + SQT)
#define OFF_V    (OFF_KT + SQT)
#define OFF_POS  (OFF_V + SQT)
// total = 5*8388608 + 3*524288 + 1048576 = 44,564,480 bytes (~42.5 MiB)

extern "C" void kernel_launch(void* const* d_in, const int* in_sizes, int n_in,
                              void* d_out, int out_size, void* d_ws, size_t ws_size,
                              hipStream_t stream) {
    const float* x   = (const float*)d_in[0];
    const float* d   = (const float*)d_in[1];
    const float* Wq  = (const float*)d_in[2];
    const float* bq  = (const float*)d_in[3];
    const float* Wk  = (const float*)d_in[4];
    const float* bk  = (const float*)d_in[5];
    const float* Wv  = (const float*)d_in[6];
    const float* bv  = (const float*)d_in[7];
    const float* rh  = (const float*)d_in[8];
    const float* rw  = (const float*)d_in[9];

    char* ws = (char*)d_ws;
    u16* xt = (u16*)(ws + OFF_XT);
    u16* dt = (u16*)(ws + OFF_DT);
    u16* wq = (u16*)(ws + OFF_WQ);
    u16* wk = (u16*)(ws + OFF_WK);
    u16* wv = (u16*)(ws + OFF_WV);
    u16* qt = (u16*)(ws + OFF_QT);
    u16* kt = (u16*)(ws + OFF_KT);
    u16* v_ = (u16*)(ws + OFF_V);
    u16* ps = (u16*)(ws + OFF_POS);

    k_prep<<<7168, 256, 0, stream>>>(x, d, Wq, Wk, Wv, rh, rw, xt, dt, wq, wk, wv, ps);
    k_proj<<<dim3(4, 8, 24), 256, 0, stream>>>(xt, dt, wq, wk, wv, bq, bk, bv, qt, kt, v_);
    k_attn<<<512, 256, 0, stream>>>(qt, kt, v_, ps, (float*)d_out);
}